// Round 1
// baseline (287.686 us; speedup 1.0000x reference)
//
#include <hip/hip_runtime.h>
#include <math.h>

#define B   16
#define M   1024
#define W   256
#define H   8
#define NW  2
#define NR  4
#define EPSF 1e-6f

// clang native vector type — accepted by __builtin_nontemporal_*
typedef float v4f __attribute__((ext_vector_type(4)));

// ---------------------------------------------------------------------------
// Kernel 1: memory-row compute only (link copy moved to hipMemcpyAsync).
// 4096 blocks x 256 threads; each wave owns one (b,m) memory row:
//   - row norm + 8 key dots (raw dot written, cosine scaling deferred)
//   - erase/write update of the row
// Traffic: ~35 MB total -> expected ~8 us.
// ---------------------------------------------------------------------------
__global__ void __launch_bounds__(256) mem_kernel(
    const float* __restrict__ memory, const float* __restrict__ keys,
    const float* __restrict__ ww,     const float* __restrict__ ev,
    const float* __restrict__ wv,
    float* __restrict__ out_mem,      float* __restrict__ out_cos,
    float* __restrict__ ws_norm) {
    int t = threadIdx.x;
    int lane = t & 63;
    int wid = t >> 6;
    int bm = blockIdx.x * 4 + wid;                 // [0, 16384)
    int b = bm >> 10;
    int m = bm & 1023;

    // ---- memory row: load + norm + key dots ------------------------------
    v4f x = __builtin_nontemporal_load(
        ((const v4f*)memory) + (size_t)bm * (W / 4) + lane);

    float acc[9];
    acc[8] = x.x * x.x + x.y * x.y + x.z * x.z + x.w * x.w;
    const v4f* kb = (const v4f*)(keys) + (size_t)b * H * (W / 4);
    #pragma unroll
    for (int h = 0; h < H; ++h) {
        v4f k = kb[h * (W / 4) + lane];
        acc[h] = x.x * k.x + x.y * k.y + x.z * k.z + x.w * k.w;
    }
    #pragma unroll
    for (int off = 1; off < 64; off <<= 1) {
        #pragma unroll
        for (int j = 0; j < 9; ++j) acc[j] += __shfl_xor(acc[j], off);
    }

    // ---- erase / write update --------------------------------------------
    float w0 = ww[(b * NW + 0) * M + m];
    float w1 = ww[(b * NW + 1) * M + m];
    const v4f* e0p = (const v4f*)(ev) + (size_t)(b * NW) * (W / 4);
    const v4f* v0p = (const v4f*)(wv) + (size_t)(b * NW) * (W / 4);
    v4f e0 = e0p[lane], e1 = e0p[(W / 4) + lane];
    v4f v0 = v0p[lane], v1 = v0p[(W / 4) + lane];
    v4f r;
    {
        float e;
        e = fminf(fmaxf(w0 * e0.x + w1 * e1.x, 0.f), 1.f);
        r.x = x.x * (1.f - e) + w0 * v0.x + w1 * v1.x;
        e = fminf(fmaxf(w0 * e0.y + w1 * e1.y, 0.f), 1.f);
        r.y = x.y * (1.f - e) + w0 * v0.y + w1 * v1.y;
        e = fminf(fmaxf(w0 * e0.z + w1 * e1.z, 0.f), 1.f);
        r.z = x.z * (1.f - e) + w0 * v0.z + w1 * v1.z;
        e = fminf(fmaxf(w0 * e0.w + w1 * e1.w, 0.f), 1.f);
        r.w = x.w * (1.f - e) + w0 * v0.w + w1 * v1.w;
    }
    __builtin_nontemporal_store(r,
        ((v4f*)out_mem) + (size_t)bm * (W / 4) + lane);

    // raw dot per head (cosine scale deferred to kernel 2)
    if (lane < H) {
        float d = acc[0];
        #pragma unroll
        for (int h = 1; h < H; ++h)
            if (lane == h) d = acc[h];
        out_cos[(size_t)(b * H + lane) * M + m] = d;
    }
    if (lane == 0) ws_norm[bm] = sqrtf(acc[8] + EPSF);
}

// ---------------------------------------------------------------------------
// Kernel 2: [0,128) softmax+cosine per (b,h) | [128,144) misc | [144,176) prec
// ---------------------------------------------------------------------------
__global__ void __launch_bounds__(256) finish_kernel(
    const float* __restrict__ keys, const float* __restrict__ strengths,
    const float* __restrict__ ws_norm, const float* __restrict__ ww,
    const float* __restrict__ fg,   const float* __restrict__ rw,
    const float* __restrict__ pu,   const float* __restrict__ rv,
    float* __restrict__ cosr,       float* __restrict__ out_prec,
    float* __restrict__ out_usage,  float* __restrict__ out_read) {
    int blk = blockIdx.x;
    int t = threadIdx.x;
    int wid = t >> 6;

    if (blk < B * H) {
        // ------------------ softmax + cosine scaling ----------------------
        int bh = blk;
        int b = bh >> 3;
        __shared__ float skn[4];
        __shared__ float sm[4];
        __shared__ float ss[4];

        float kv = keys[(size_t)bh * W + t];
        float s = kv * kv;
        #pragma unroll
        for (int off = 1; off < 64; off <<= 1) s += __shfl_xor(s, off);
        if ((t & 63) == 0) skn[wid] = s;
        __syncthreads();
        float kn = sqrtf(skn[0] + skn[1] + skn[2] + skn[3] + EPSF);
        float sp = log1pf(expf(strengths[bh]));

        float* row = cosr + (size_t)bh * M;
        float v[4];
        #pragma unroll
        for (int c = 0; c < 4; ++c) {
            int m = t + c * 256;
            float d = row[m];
            float nm = ws_norm[b * M + m];
            v[c] = d / (nm * kn + EPSF) * sp;
        }

        float mx = fmaxf(fmaxf(v[0], v[1]), fmaxf(v[2], v[3]));
        #pragma unroll
        for (int off = 1; off < 64; off <<= 1) mx = fmaxf(mx, __shfl_xor(mx, off));
        if ((t & 63) == 0) sm[wid] = mx;
        __syncthreads();
        mx = fmaxf(fmaxf(sm[0], sm[1]), fmaxf(sm[2], sm[3]));

        float sum = 0.f;
        #pragma unroll
        for (int c = 0; c < 4; ++c) { v[c] = expf(v[c] - mx); sum += v[c]; }
        #pragma unroll
        for (int off = 1; off < 64; off <<= 1) sum += __shfl_xor(sum, off);
        if ((t & 63) == 0) ss[wid] = sum;
        __syncthreads();
        float inv = 1.f / (ss[0] + ss[1] + ss[2] + ss[3]);

        #pragma unroll
        for (int c = 0; c < 4; ++c) row[t + c * 256] = v[c] * inv;
        return;
    }

    if (blk < B * H + B) {
        // ------------------ usage + read_output ---------------------------
        int b = blk - B * H;
        __shared__ float spm[4][NR];

        float f[NR];
        #pragma unroll
        for (int n = 0; n < NR; ++n) f[n] = fg[b * NR + n];

        float part[NR] = {0.f, 0.f, 0.f, 0.f};
        #pragma unroll
        for (int c = 0; c < 4; ++c) {
            int m = t + c * 256;
            float u = pu[b * M + m] + ww[(b * NW + 0) * M + m]
                                    + ww[(b * NW + 1) * M + m];
            #pragma unroll
            for (int n = 0; n < NR; ++n) {
                float r = rw[(size_t)(b * NR + n) * M + m];
                part[n] += r;
                u -= r * f[n];
            }
            out_usage[b * M + m] = fminf(fmaxf(u, 0.f), 1.f);
        }

        #pragma unroll
        for (int off = 1; off < 64; off <<= 1) {
            #pragma unroll
            for (int n = 0; n < NR; ++n) part[n] += __shfl_xor(part[n], off);
        }
        if ((t & 63) == 0) {
            #pragma unroll
            for (int n = 0; n < NR; ++n) spm[wid][n] = part[n];
        }
        __syncthreads();

        float ro = 0.f;
        #pragma unroll
        for (int n = 0; n < NR; ++n) {
            float rs = spm[0][n] + spm[1][n] + spm[2][n] + spm[3][n];
            ro += rs * rv[(size_t)(b * NR + n) * W + t];
        }
        out_read[b * W + t] = ro;
        return;
    }

    // ---------------------- precedence := write_weights -------------------
    {
        int i = (blk - (B * H + B)) * 256 + t;     // [0, 8192)
        ((v4f*)out_prec)[i] = ((const v4f*)ww)[i];
    }
}

// ---------------------------------------------------------------------------
extern "C" void kernel_launch(void* const* d_in, const int* in_sizes, int n_in,
                              void* d_out, int out_size, void* d_ws, size_t ws_size,
                              hipStream_t stream) {
    const float* memory        = (const float*)d_in[0];
    const float* keys          = (const float*)d_in[1];
    const float* strengths     = (const float*)d_in[2];
    const float* write_weights = (const float*)d_in[3];
    const float* free_gate     = (const float*)d_in[4];
    const float* read_weights  = (const float*)d_in[5];
    const float* prev_link     = (const float*)d_in[6];
    const float* prev_usage    = (const float*)d_in[8];
    const float* erase_vectors = (const float*)d_in[9];
    const float* write_vectors = (const float*)d_in[10];
    const float* read_vectors  = (const float*)d_in[11];

    float* out = (float*)d_out;
    float* out_mem   = out;                       // [B,M,W]     4,194,304
    float* out_cos   = out + 4194304;             // [B,H,M]       131,072
    float* out_link  = out + 4325376;             // [B,NW,M,M] 33,554,432
    float* out_prec  = out + 37879808;            // [B,NW,M]       32,768
    float* out_usage = out + 37912576;            // [B,M]          16,384
    float* out_read  = out + 37928960;            // [B,W]           4,096

    float* ws_norm = (float*)d_ws;                // [B*M] = 16,384 floats

    // link = prev_link passthrough: 134 MB via known-good D2D copy engine.
    hipMemcpyAsync(out_link, prev_link, (size_t)33554432 * sizeof(float),
                   hipMemcpyDeviceToDevice, stream);

    hipLaunchKernelGGL(mem_kernel, dim3(4096), dim3(256), 0, stream,
                       memory, keys, write_weights,
                       erase_vectors, write_vectors,
                       out_mem, out_cos, ws_norm);
    hipLaunchKernelGGL(finish_kernel, dim3(B * H + B + 32), dim3(256), 0,
                       stream,
                       keys, strengths, ws_norm, write_weights, free_gate,
                       read_weights, prev_usage, read_vectors,
                       out_cos, out_prec, out_usage, out_read);
}